// Round 7
// baseline (104.232 us; speedup 1.0000x reference)
//
#include <hip/hip_runtime.h>
#include <math.h>

// Problem constants (match reference)
#define Lp 1024
#define Bp 64
#define Tt 128          // tile rows
#define NTILE 8         // Lp / Tt
#define NPAIR 36        // NTILE*(NTILE+1)/2 triangular tile pairs
#define NBLK (Bp * NPAIR)   // 2304 main blocks

typedef float v2 __attribute__((ext_vector_type(2)));
static __device__ __forceinline__ v2 splat2(float s) { v2 r; r.x = s; r.y = s; return r; }
static __device__ __forceinline__ v2 lo2(float4 v)   { v2 r; r.x = v.x; r.y = v.y; return r; }
static __device__ __forceinline__ v2 hi2(float4 v)   { v2 r; r.x = v.z; r.y = v.w; return r; }

// Identity: sum_{pairs} mi*mj*(dx-dy)^2
//         = sum mi*mj*(d2x+d2y)  -  2*sum mi*mj*dx*dy   (first term O(L) via moments)
// Cross term per pair: d2x = -2*ux, ux = xi.xj - |xi|^2/2 - |xj|^2/2  (ux <= 0 exact)
//   sqrt(d2x*d2y) = 2*sqrt(ux*uy); the 2 folds into the block-partial scale.
//
// Pass 1 (prep): transpose to packed [B][L] float4 records (x0,x1,x2,-|x|^2/2),
// mask array, stripe moments; zero the ticket counter. Main then stages with
// 3 coalesced loads/thread and no staging math; final is fused into the last
// main block (ticket pattern) -- no third dispatch.
__global__ __launch_bounds__(128) void drmsd_prep(
    const float* __restrict__ x, const float* __restrict__ y,
    float4* __restrict__ xt, float4* __restrict__ yt,
    float* __restrict__ msb, float* __restrict__ moments,
    int* __restrict__ counter)
{
    __shared__ float mred[2][9];
    const int b = blockIdx.x;      // batch
    const int s = blockIdx.y;      // stripe 0..7
    const int t = threadIdx.x;     // row within stripe 0..127

    if (b == 0 && s == 0 && t == 0) *counter = 0;

    const int row = s * Tt + t;
    const float* px = x + (size_t)row * (Bp * 3) + (size_t)b * 3;
    const float* py = y + (size_t)row * (Bp * 3) + (size_t)b * 3;
    const float x0 = px[0], x1 = px[1], x2 = px[2];
    const float y0 = py[0], y1 = py[1], y2 = py[2];
    const float qxr = fmaf(x0, x0, fmaf(x1, x1, x2 * x2));
    const float qyr = fmaf(y0, y0, fmaf(y1, y1, y2 * y2));
    const float m   = ((y0 + y1 + y2) != 0.0f) ? 1.0f : 0.0f;

    float4 rx; rx.x = x0; rx.y = x1; rx.z = x2; rx.w = -0.5f * qxr;
    float4 ry; ry.x = y0; ry.y = y1; ry.z = y2; ry.w = -0.5f * qyr;
    xt[(size_t)b * Lp + row] = rx;          // coalesced float4
    yt[(size_t)b * Lp + row] = ry;
    msb[(size_t)b * Lp + row] = m;

    // stripe moments: Sx(3), Qx, Sy(3), Qy, M
    float v[9];
    v[0] = m * x0; v[1] = m * x1; v[2] = m * x2; v[3] = m * qxr;
    v[4] = m * y0; v[5] = m * y1; v[6] = m * y2; v[7] = m * qyr;
    v[8] = m;
#pragma unroll
    for (int k = 0; k < 9; ++k) {
#pragma unroll
        for (int off = 32; off > 0; off >>= 1)
            v[k] += __shfl_down(v[k], off, 64);
    }
    const int wave = t >> 6;
    if ((t & 63) == 0) {
#pragma unroll
        for (int k = 0; k < 9; ++k) mred[wave][k] = v[k];
    }
    __syncthreads();
    if (t < 9)
        moments[(size_t)(s * 9 + t) * Bp + b] = mred[0][t] + mred[1][t];
}

__global__ __launch_bounds__(256) void drmsd_main(
    const float4* __restrict__ xt, const float4* __restrict__ yt,
    const float* __restrict__ msb,
    float* __restrict__ partials, const float* __restrict__ moments,
    int* __restrict__ counter, float* __restrict__ out)
{
    __shared__ __align__(16) float xsx[2][Tt], xsy[2][Tt], xsz[2][Tt];
    __shared__ __align__(16) float ysx[2][Tt], ysy[2][Tt], ysz[2][Tt];
    __shared__ __align__(16) float nhx[2][Tt], nhy[2][Tt];
    __shared__ __align__(16) float ms[2][Tt];
    __shared__ float red[4];
    __shared__ int islast;

    const int b = blockIdx.x;      // batch
    const int p = blockIdx.y;      // triangular pair index 0..35
    const int t = threadIdx.x;

    // decode p -> (ti, tj), ti <= tj
    int ti = 0, base = 0;
    while (p >= base + (NTILE - ti)) { base += (NTILE - ti); ++ti; }
    const int tj = ti + (p - base);

    // ---- stage from packed records: 3 coalesced loads, no math
    {
        const int r     = t & (Tt - 1);
        const int which = t >> 7;
        const int tile  = which ? tj : ti;
        const int row   = tile * Tt + r;
        const float4 rx = xt[(size_t)b * Lp + row];
        const float4 ry = yt[(size_t)b * Lp + row];
        xsx[which][r] = rx.x; xsy[which][r] = rx.y; xsz[which][r] = rx.z;
        nhx[which][r] = rx.w;
        ysx[which][r] = ry.x; ysy[which][r] = ry.y; ysz[which][r] = ry.z;
        nhy[which][r] = ry.w;
        ms[which][r]  = msb[(size_t)b * Lp + row];
    }
    __syncthreads();

    const int jc = (t & 15) << 2;     // first of 4 adjacent j columns
    const int rg = t >> 4;            // 0..15

    float total = 0.0f;

#pragma unroll
    for (int half = 0; half < 2; ++half) {
        const int i0 = half * 64 + rg * 4;
        const float4 v_xx = *(const float4*)&xsx[0][i0];
        const float4 v_xy = *(const float4*)&xsy[0][i0];
        const float4 v_xz = *(const float4*)&xsz[0][i0];
        const float4 v_yx = *(const float4*)&ysx[0][i0];
        const float4 v_yy = *(const float4*)&ysy[0][i0];
        const float4 v_yz = *(const float4*)&ysz[0][i0];
        const float4 v_hx = *(const float4*)&nhx[0][i0];
        const float4 v_hy = *(const float4*)&nhy[0][i0];
        const float4 v_mi = *(const float4*)&ms[0][i0];
        const float xix[4] = { v_xx.x, v_xx.y, v_xx.z, v_xx.w };
        const float xiy[4] = { v_xy.x, v_xy.y, v_xy.z, v_xy.w };
        const float xiz[4] = { v_xz.x, v_xz.y, v_xz.z, v_xz.w };
        const float yix[4] = { v_yx.x, v_yx.y, v_yx.z, v_yx.w };
        const float yiy[4] = { v_yy.x, v_yy.y, v_yy.z, v_yy.w };
        const float yiz[4] = { v_yz.x, v_yz.y, v_yz.z, v_yz.w };
        const float hxi[4] = { v_hx.x, v_hx.y, v_hx.z, v_hx.w };
        const float hyi[4] = { v_hy.x, v_hy.y, v_hy.z, v_hy.w };
        const float mir[4] = { v_mi.x, v_mi.y, v_mi.z, v_mi.w };

        v2 acc[4];
#pragma unroll
        for (int r = 0; r < 4; ++r) acc[r] = splat2(0.0f);

#pragma unroll
        for (int jj = 0; jj < 2; ++jj) {
            const int j0 = jj * 64 + jc;
            const float4 xjx4 = *(const float4*)&xsx[1][j0];
            const float4 xjy4 = *(const float4*)&xsy[1][j0];
            const float4 xjz4 = *(const float4*)&xsz[1][j0];
            const float4 yjx4 = *(const float4*)&ysx[1][j0];
            const float4 yjy4 = *(const float4*)&ysy[1][j0];
            const float4 yjz4 = *(const float4*)&ysz[1][j0];
            const float4 hxj4 = *(const float4*)&nhx[1][j0];
            const float4 hyj4 = *(const float4*)&nhy[1][j0];
            const float4 mj4  = *(const float4*)&ms[1][j0];
#pragma unroll
            for (int s = 0; s < 2; ++s) {
                const v2 xjx = s ? hi2(xjx4) : lo2(xjx4);
                const v2 xjy = s ? hi2(xjy4) : lo2(xjy4);
                const v2 xjz = s ? hi2(xjz4) : lo2(xjz4);
                const v2 yjx = s ? hi2(yjx4) : lo2(yjx4);
                const v2 yjy = s ? hi2(yjy4) : lo2(yjy4);
                const v2 yjz = s ? hi2(yjz4) : lo2(yjz4);
                const v2 hxj = s ? hi2(hxj4) : lo2(hxj4);
                const v2 hyj = s ? hi2(hyj4) : lo2(hyj4);
                const v2 mj  = s ? hi2(mj4)  : lo2(mj4);
#pragma unroll
                for (int r = 0; r < 4; ++r) {
                    v2 ux = splat2(hxi[r]) + hxj;
                    ux = splat2(xix[r]) * xjx + ux;
                    ux = splat2(xiy[r]) * xjy + ux;
                    ux = splat2(xiz[r]) * xjz + ux;
                    v2 uy = splat2(hyi[r]) + hyj;
                    uy = splat2(yix[r]) * yjx + uy;
                    uy = splat2(yiy[r]) * yjy + uy;
                    uy = splat2(yiz[r]) * yjz + uy;
                    const v2 pr = ux * uy;           // >= 0 up to rounding
                    v2 sq;                           // |.| folds into VOP3 mod
                    sq.x = __builtin_amdgcn_sqrtf(__builtin_fabsf(pr.x));
                    sq.y = __builtin_amdgcn_sqrtf(__builtin_fabsf(pr.y));
                    acc[r] = mj * sq + acc[r];       // col mask
                }
            }
        }
#pragma unroll
        for (int r = 0; r < 4; ++r)
            total = fmaf(acc[r].x + acc[r].y, mir[r], total);   // row mask
    }

    // ---- block reduction + partial write + ticket ----
#pragma unroll
    for (int off = 32; off > 0; off >>= 1)
        total += __shfl_down(total, off, 64);
    const int wave = t >> 6;
    if ((t & 63) == 0) red[wave] = total;
    __syncthreads();
    if (t == 0) {
        float s = red[0] + red[1] + red[2] + red[3];
        // x2: sqrt(d2x*d2y) = 2*sqrt(ux*uy); extra x2 off-diag for both orders
        s *= (ti != tj) ? 4.0f : 2.0f;
        partials[(size_t)p * Bp + b] = s;
        __threadfence();                       // release partial
        const int ticket = atomicAdd(counter, 1);
        islast = (ticket == NBLK - 1) ? 1 : 0;
    }
    __syncthreads();

    // ---- fused final: exactly one block runs this, after all partials land
    if (islast) {
        __threadfence();                       // acquire
        if (t < Bp) {
            const int bb = t;                  // one batch per lane (wave 0)
            double cross = 0.0;
#pragma unroll
            for (int pp = 0; pp < NPAIR; ++pp)
                cross += (double)partials[(size_t)pp * Bp + bb];
            float mo[9];
#pragma unroll
            for (int k = 0; k < 9; ++k) mo[k] = 0.0f;
#pragma unroll
            for (int s = 0; s < NTILE; ++s) {
#pragma unroll
                for (int k = 0; k < 9; ++k)
                    mo[k] += moments[(size_t)(s * 9 + k) * Bp + bb];
            }
            const double sx0 = mo[0], sx1 = mo[1], sx2 = mo[2], qx = mo[3];
            const double sy0 = mo[4], sy1 = mo[5], sy2 = mo[6], qy = mo[7];
            const double M   = mo[8];
            const double term1 = 2.0 * M * (qx + qy)
                - 2.0 * (sx0*sx0 + sx1*sx1 + sx2*sx2 + sy0*sy0 + sy1*sy1 + sy2*sy2);
            double su = term1 - 2.0 * cross;
            su = su > 0.0 ? su : 0.0;          // guard rounding when x == y
            double pb = sqrt(su);
#pragma unroll
            for (int off = 32; off > 0; off >>= 1)
                pb += __shfl_down(pb, off, 64);
            if (t == 0) {
                const double denom = sqrt((double)Lp * (double)Lp / 2.0 - (double)Lp);
                out[0] = (float)(pb / denom / (double)Bp);
            }
        }
    }
}

extern "C" void kernel_launch(void* const* d_in, const int* in_sizes, int n_in,
                              void* d_out, int out_size, void* d_ws, size_t ws_size,
                              hipStream_t stream) {
    const float* x = (const float*)d_in[0];
    const float* y = (const float*)d_in[1];
    float* out = (float*)d_out;

    // workspace carve-up (d_ws is >= 16B aligned)
    float4* xt = (float4*)d_ws;                       // Bp*Lp float4 = 1 MB
    float4* yt = xt + (size_t)Bp * Lp;                // 1 MB
    float*  msb = (float*)(yt + (size_t)Bp * Lp);     // 256 KB
    float*  partials = msb + (size_t)Bp * Lp;         // NPAIR*Bp floats
    float*  moments  = partials + NPAIR * Bp;         // NTILE*9*Bp floats
    int*    counter  = (int*)(moments + NTILE * 9 * Bp);

    dim3 gprep(Bp, NTILE);
    drmsd_prep<<<gprep, 128, 0, stream>>>(x, y, xt, yt, msb, moments, counter);
    dim3 gmain(Bp, NPAIR);
    drmsd_main<<<gmain, 256, 0, stream>>>(xt, yt, msb, partials, moments,
                                          counter, out);
}

// Round 8
// 73.223 us; speedup vs baseline: 1.4235x; 1.4235x over previous
//
#include <hip/hip_runtime.h>
#include <math.h>

// Problem constants (match reference)
#define Lp 1024
#define Bp 64
#define NTILE 8         // 128-row tiles
#define NPAIR 36        // triangular tile pairs
#define NQ 8            // work-split blocks per batch
#define UPB 9           // half-tile units per block (72 units / 8 blocks)

typedef float v2 __attribute__((ext_vector_type(2)));
static __device__ __forceinline__ v2 splat2(float s) { v2 r; r.x = s; r.y = s; return r; }
static __device__ __forceinline__ v2 lo2(float4 v)   { v2 r; r.x = v.x; r.y = v.y; return r; }
static __device__ __forceinline__ v2 hi2(float4 v)   { v2 r; r.x = v.z; r.y = v.w; return r; }

// Identity: sum_{pairs} mi*mj*(dx-dy)^2
//         = sum mi*mj*(d2x+d2y)  -  2*sum mi*mj*dx*dy   (first term O(L) via moments)
// Cross term per pair: d2x = -2*ux, ux = xi.xj - |xi|^2/2 - |xj|^2/2  (ux <= 0 exact)
//   sqrt(d2x*d2y) = 2*sqrt(ux*uy); the 2 folds into the partial scale.
//
// Structure (R7 lesson: per-block device-scope fences cost ~29 us -- use
// dispatch-boundary release/acquire instead):
//   prep : pack [B][L] float4 records (x,y,z,-|r|^2/2) + stripe moments.
//   main : 64 batches x 8 splits; block stages the WHOLE batch in LDS (36 KB)
//          once, then computes 9 half-tile units (72 = 36 pairs x 2 halves)
//          with no further barriers -- staging/ramp amortized 9x vs R5.
//   final: 1 wave, double-precision combine.
__global__ __launch_bounds__(128) void drmsd_prep(
    const float* __restrict__ x, const float* __restrict__ y,
    float4* __restrict__ xt, float4* __restrict__ yt,
    float* __restrict__ moments)
{
    __shared__ float mred[2][9];
    const int b = blockIdx.x;      // batch
    const int s = blockIdx.y;      // stripe 0..7
    const int t = threadIdx.x;     // row within stripe 0..127

    const int row = s * 128 + t;
    const float* px = x + (size_t)row * (Bp * 3) + (size_t)b * 3;
    const float* py = y + (size_t)row * (Bp * 3) + (size_t)b * 3;
    const float x0 = px[0], x1 = px[1], x2 = px[2];
    const float y0 = py[0], y1 = py[1], y2 = py[2];
    const float qxr = fmaf(x0, x0, fmaf(x1, x1, x2 * x2));
    const float qyr = fmaf(y0, y0, fmaf(y1, y1, y2 * y2));
    const float m   = ((y0 + y1 + y2) != 0.0f) ? 1.0f : 0.0f;

    float4 rx; rx.x = x0; rx.y = x1; rx.z = x2; rx.w = -0.5f * qxr;
    float4 ry; ry.x = y0; ry.y = y1; ry.z = y2; ry.w = -0.5f * qyr;
    xt[(size_t)b * Lp + row] = rx;          // coalesced float4
    yt[(size_t)b * Lp + row] = ry;

    // stripe moments: Sx(3), Qx, Sy(3), Qy, M
    float v[9];
    v[0] = m * x0; v[1] = m * x1; v[2] = m * x2; v[3] = m * qxr;
    v[4] = m * y0; v[5] = m * y1; v[6] = m * y2; v[7] = m * qyr;
    v[8] = m;
#pragma unroll
    for (int k = 0; k < 9; ++k) {
#pragma unroll
        for (int off = 32; off > 0; off >>= 1)
            v[k] += __shfl_down(v[k], off, 64);
    }
    const int wave = t >> 6;
    if ((t & 63) == 0) {
#pragma unroll
        for (int k = 0; k < 9; ++k) mred[wave][k] = v[k];
    }
    __syncthreads();
    if (t < 9)
        moments[(size_t)(s * 9 + t) * Bp + b] = mred[0][t] + mred[1][t];
}

__global__ __launch_bounds__(256) void drmsd_main(
    const float4* __restrict__ xt, const float4* __restrict__ yt,
    float* __restrict__ partials)
{
    __shared__ __align__(16) float xsx[Lp], xsy[Lp], xsz[Lp], nhx[Lp];
    __shared__ __align__(16) float ysx[Lp], ysy[Lp], ysz[Lp], nhy[Lp];
    __shared__ __align__(16) float ms[Lp];
    __shared__ float red[4];

    const int b = blockIdx.x;      // batch
    const int q = blockIdx.y;      // split 0..7 (same-batch splits share an XCD)
    const int t = threadIdx.x;

    // ---- stage the whole batch: 8 coalesced float4 loads per thread
#pragma unroll
    for (int k = 0; k < 4; ++k) {
        const int row = t + k * 256;
        const float4 rx = xt[(size_t)b * Lp + row];
        const float4 ry = yt[(size_t)b * Lp + row];
        xsx[row] = rx.x; xsy[row] = rx.y; xsz[row] = rx.z; nhx[row] = rx.w;
        ysx[row] = ry.x; ysy[row] = ry.y; ysz[row] = ry.z; nhy[row] = ry.w;
        ms[row]  = ((ry.x + ry.y + ry.z) != 0.0f) ? 1.0f : 0.0f;
    }
    __syncthreads();

    const int rg  = t >> 4;          // 0..15: i-group (4 rows) within 64-row half
    const int jcl = (t & 15) << 3;   // 8 j-columns within 128-col tile

    float tdiag = 0.0f, toff = 0.0f;

#pragma unroll 1
    for (int k = 0; k < UPB; ++k) {
        const int u = q * UPB + k;   // half-tile unit 0..71
        const int p = u >> 1, h = u & 1;
        int ti = 0, base = 0;        // decode pair p -> (ti, tj), ti <= tj
        while (p >= base + (NTILE - ti)) { base += (NTILE - ti); ++ti; }
        const int tj = ti + (p - base);

        const int ib = ti * 128 + h * 64 + rg * 4;   // 4 i-rows
        const int jb = tj * 128 + jcl;               // 8 j-cols

        const float4 v_xx = *(const float4*)&xsx[ib];
        const float4 v_xy = *(const float4*)&xsy[ib];
        const float4 v_xz = *(const float4*)&xsz[ib];
        const float4 v_yx = *(const float4*)&ysx[ib];
        const float4 v_yy = *(const float4*)&ysy[ib];
        const float4 v_yz = *(const float4*)&ysz[ib];
        const float4 v_hx = *(const float4*)&nhx[ib];
        const float4 v_hy = *(const float4*)&nhy[ib];
        const float4 v_mi = *(const float4*)&ms[ib];
        const float xix[4] = { v_xx.x, v_xx.y, v_xx.z, v_xx.w };
        const float xiy[4] = { v_xy.x, v_xy.y, v_xy.z, v_xy.w };
        const float xiz[4] = { v_xz.x, v_xz.y, v_xz.z, v_xz.w };
        const float yix[4] = { v_yx.x, v_yx.y, v_yx.z, v_yx.w };
        const float yiy[4] = { v_yy.x, v_yy.y, v_yy.z, v_yy.w };
        const float yiz[4] = { v_yz.x, v_yz.y, v_yz.z, v_yz.w };
        const float hxi[4] = { v_hx.x, v_hx.y, v_hx.z, v_hx.w };
        const float hyi[4] = { v_hy.x, v_hy.y, v_hy.z, v_hy.w };
        const float mir[4] = { v_mi.x, v_mi.y, v_mi.z, v_mi.w };

        v2 acc[4];
#pragma unroll
        for (int r = 0; r < 4; ++r) acc[r] = splat2(0.0f);

#pragma unroll
        for (int jj = 0; jj < 2; ++jj) {
            const int j0 = jb + jj * 4;
            const float4 xjx4 = *(const float4*)&xsx[j0];
            const float4 xjy4 = *(const float4*)&xsy[j0];
            const float4 xjz4 = *(const float4*)&xsz[j0];
            const float4 yjx4 = *(const float4*)&ysx[j0];
            const float4 yjy4 = *(const float4*)&ysy[j0];
            const float4 yjz4 = *(const float4*)&ysz[j0];
            const float4 hxj4 = *(const float4*)&nhx[j0];
            const float4 hyj4 = *(const float4*)&nhy[j0];
            const float4 mj4  = *(const float4*)&ms[j0];
#pragma unroll
            for (int s = 0; s < 2; ++s) {
                const v2 xjx = s ? hi2(xjx4) : lo2(xjx4);
                const v2 xjy = s ? hi2(xjy4) : lo2(xjy4);
                const v2 xjz = s ? hi2(xjz4) : lo2(xjz4);
                const v2 yjx = s ? hi2(yjx4) : lo2(yjx4);
                const v2 yjy = s ? hi2(yjy4) : lo2(yjy4);
                const v2 yjz = s ? hi2(yjz4) : lo2(yjz4);
                const v2 hxj = s ? hi2(hxj4) : lo2(hxj4);
                const v2 hyj = s ? hi2(hyj4) : lo2(hyj4);
                const v2 mj  = s ? hi2(mj4)  : lo2(mj4);
#pragma unroll
                for (int r = 0; r < 4; ++r) {
                    v2 ux = splat2(hxi[r]) + hxj;
                    ux = splat2(xix[r]) * xjx + ux;
                    ux = splat2(xiy[r]) * xjy + ux;
                    ux = splat2(xiz[r]) * xjz + ux;
                    v2 uy = splat2(hyi[r]) + hyj;
                    uy = splat2(yix[r]) * yjx + uy;
                    uy = splat2(yiy[r]) * yjy + uy;
                    uy = splat2(yiz[r]) * yjz + uy;
                    const v2 pr = ux * uy;           // >= 0 up to rounding
                    v2 sq;                           // |.| folds into VOP3 mod
                    sq.x = __builtin_amdgcn_sqrtf(__builtin_fabsf(pr.x));
                    sq.y = __builtin_amdgcn_sqrtf(__builtin_fabsf(pr.y));
                    acc[r] = mj * sq + acc[r];       // col mask
                }
            }
        }
        float us = 0.0f;
#pragma unroll
        for (int r = 0; r < 4; ++r)
            us = fmaf(acc[r].x + acc[r].y, mir[r], us);   // row mask
        if (ti == tj) tdiag += us; else toff += us;
    }
    // x2 from sqrt(d2x*d2y)=2*sqrt(ux*uy); extra x2 off-diag for both orders
    float total = fmaf(toff, 4.0f, tdiag * 2.0f);

    // ---- block reduction ----
#pragma unroll
    for (int off = 32; off > 0; off >>= 1)
        total += __shfl_down(total, off, 64);
    const int wave = t >> 6;
    if ((t & 63) == 0) red[wave] = total;
    __syncthreads();
    if (t == 0)
        partials[(size_t)q * Bp + b] = red[0] + red[1] + red[2] + red[3];
}

// Single wave: combine closed-form (d2x+d2y) term with cross-term partials.
__global__ __launch_bounds__(64) void drmsd_final(
    const float* __restrict__ partials, const float* __restrict__ moments,
    float* __restrict__ out)
{
    const int b = threadIdx.x;   // 0..63, one batch per lane
    double cross = 0.0;
#pragma unroll
    for (int qq = 0; qq < NQ; ++qq)
        cross += (double)partials[(size_t)qq * Bp + b];   // coalesced

    double mo[9];
#pragma unroll
    for (int k = 0; k < 9; ++k) mo[k] = 0.0;
#pragma unroll
    for (int s = 0; s < NTILE; ++s) {
#pragma unroll
        for (int k = 0; k < 9; ++k)
            mo[k] += (double)moments[(size_t)(s * 9 + k) * Bp + b];  // coalesced
    }
    const double sx0 = mo[0], sx1 = mo[1], sx2 = mo[2], qx = mo[3];
    const double sy0 = mo[4], sy1 = mo[5], sy2 = mo[6], qy = mo[7];
    const double M   = mo[8];
    const double term1 = 2.0 * M * (qx + qy)
        - 2.0 * (sx0*sx0 + sx1*sx1 + sx2*sx2 + sy0*sy0 + sy1*sy1 + sy2*sy2);

    double su = term1 - 2.0 * cross;
    su = su > 0.0 ? su : 0.0;        // guard rounding when x == y
    double pb = sqrt(su);
#pragma unroll
    for (int off = 32; off > 0; off >>= 1)
        pb += __shfl_down(pb, off, 64);
    if (b == 0) {
        const double denom = sqrt((double)Lp * (double)Lp / 2.0 - (double)Lp);
        out[0] = (float)(pb / denom / (double)Bp);
    }
}

extern "C" void kernel_launch(void* const* d_in, const int* in_sizes, int n_in,
                              void* d_out, int out_size, void* d_ws, size_t ws_size,
                              hipStream_t stream) {
    const float* x = (const float*)d_in[0];
    const float* y = (const float*)d_in[1];
    float* out = (float*)d_out;

    // workspace carve-up (d_ws is >= 16B aligned)
    float4* xt = (float4*)d_ws;                       // Bp*Lp float4 = 1 MB
    float4* yt = xt + (size_t)Bp * Lp;                // 1 MB
    float*  partials = (float*)(yt + (size_t)Bp * Lp);// NQ*Bp floats
    float*  moments  = partials + NQ * Bp;            // NTILE*9*Bp floats

    dim3 gprep(Bp, NTILE);
    drmsd_prep<<<gprep, 128, 0, stream>>>(x, y, xt, yt, moments);
    dim3 gmain(Bp, NQ);
    drmsd_main<<<gmain, 256, 0, stream>>>(xt, yt, partials);
    drmsd_final<<<1, 64, 0, stream>>>(partials, moments, out);
}

// Round 9
// 71.343 us; speedup vs baseline: 1.4610x; 1.0263x over previous
//
#include <hip/hip_runtime.h>
#include <math.h>

// Problem constants (match reference)
#define Lp 1024
#define Bp 64
#define Tt 128          // tile rows
#define NTILE 8         // Lp / Tt
#define NPAIR 36        // NTILE*(NTILE+1)/2 triangular tile pairs
#define NCB 18          // compute blocks per batch (2 pairs each)

typedef float v2 __attribute__((ext_vector_type(2)));
static __device__ __forceinline__ v2 splat2(float s) { v2 r; r.x = s; r.y = s; return r; }
static __device__ __forceinline__ v2 lo2(float4 v)   { v2 r; r.x = v.x; r.y = v.y; return r; }
static __device__ __forceinline__ v2 hi2(float4 v)   { v2 r; r.x = v.z; r.y = v.w; return r; }

// Identity: sum_{pairs} mi*mj*(dx-dy)^2
//         = sum mi*mj*(d2x+d2y)  -  2*sum mi*mj*dx*dy   (first term O(L) via moments)
// Cross term per pair: d2x = -2*ux, ux = xi.xj - |xi|^2/2 - |xj|^2/2  (ux <= 0 exact)
//   sqrt(d2x*d2y) = 2*sqrt(ux*uy); the 2 folds into the partial scale.
//
// R8 lesson ledger: ticket-fence final = -35 us (R7); whole-batch LDS = -5 us
// (R8). This round: R5 structure (best, 68.7) with 2 tile-pairs per block ->
// grid (64,19) = 1216 blocks = 19 waves/CU (was 37 -> two scheduling rounds).
__global__ __launch_bounds__(256) void drmsd_main(
    const float* __restrict__ x, const float* __restrict__ y,
    float* __restrict__ partials, float* __restrict__ moments)
{
    __shared__ __align__(16) float xsx[4][Tt], xsy[4][Tt], xsz[4][Tt];
    __shared__ __align__(16) float ysx[4][Tt], ysy[4][Tt], ysz[4][Tt];
    __shared__ __align__(16) float nhx[4][Tt], nhy[4][Tt];
    __shared__ __align__(16) float ms[4][Tt];
    __shared__ float red[4];
    __shared__ float mred[4][9];

    const int b = blockIdx.x;      // batch
    const int g = blockIdx.y;      // 0..17 compute (pairs 2g,2g+1), 18 = moments
    const int t = threadIdx.x;

    if (g == NCB) {
        // ---- moment block: Sx(3), Qx, Sy(3), Qy, M for batch b ----
        float v[9];
#pragma unroll
        for (int k = 0; k < 9; ++k) v[k] = 0.0f;
#pragma unroll
        for (int k = 0; k < 4; ++k) {
            const int row = t + k * 256;
            const float* px = x + (size_t)row * (Bp * 3) + (size_t)b * 3;
            const float* py = y + (size_t)row * (Bp * 3) + (size_t)b * 3;
            const float x0 = px[0], x1 = px[1], x2 = px[2];
            const float y0 = py[0], y1 = py[1], y2 = py[2];
            const float m = ((y0 + y1 + y2) != 0.0f) ? 1.0f : 0.0f;
            v[0] += m * x0; v[1] += m * x1; v[2] += m * x2;
            v[3] = fmaf(m, fmaf(x0, x0, fmaf(x1, x1, x2 * x2)), v[3]);
            v[4] += m * y0; v[5] += m * y1; v[6] += m * y2;
            v[7] = fmaf(m, fmaf(y0, y0, fmaf(y1, y1, y2 * y2)), v[7]);
            v[8] += m;
        }
#pragma unroll
        for (int k = 0; k < 9; ++k) {
#pragma unroll
            for (int off = 32; off > 0; off >>= 1)
                v[k] += __shfl_down(v[k], off, 64);
        }
        const int wave = t >> 6;
        if ((t & 63) == 0) {
#pragma unroll
            for (int k = 0; k < 9; ++k) mred[wave][k] = v[k];
        }
        __syncthreads();
        if (t < 9)
            moments[(size_t)b * 9 + t] =
                mred[0][t] + mred[1][t] + mred[2][t] + mred[3][t];
        return;
    }

    // decode pair p0 = 2g -> (ti0, tj0); p1 = p0+1 follows in triangular order
    const int p0 = g * 2;
    int ti0 = 0, base = 0;
    while (p0 >= base + (NTILE - ti0)) { base += (NTILE - ti0); ++ti0; }
    const int tj0 = ti0 + (p0 - base);
    int ti1, tj1;
    if (tj0 < NTILE - 1) { ti1 = ti0; tj1 = tj0 + 1; }
    else                 { ti1 = ti0 + 1; tj1 = ti1; }

    // ---- stage 4 tile slots (i0, j0, i1, j1): 2 rows per thread
#pragma unroll
    for (int k = 0; k < 2; ++k) {
        const int idx  = t + k * 256;      // 0..511
        const int slot = idx >> 7;         // 0..3
        const int r    = idx & (Tt - 1);
        const int tile = (slot == 0) ? ti0 : (slot == 1) ? tj0
                       : (slot == 2) ? ti1 : tj1;
        const int row  = tile * Tt + r;
        const float* px = x + (size_t)row * (Bp * 3) + (size_t)b * 3;
        const float* py = y + (size_t)row * (Bp * 3) + (size_t)b * 3;
        const float x0 = px[0], x1 = px[1], x2 = px[2];
        const float y0 = py[0], y1 = py[1], y2 = py[2];
        xsx[slot][r] = x0; xsy[slot][r] = x1; xsz[slot][r] = x2;
        ysx[slot][r] = y0; ysy[slot][r] = y1; ysz[slot][r] = y2;
        nhx[slot][r] = -0.5f * fmaf(x0, x0, fmaf(x1, x1, x2 * x2));
        nhy[slot][r] = -0.5f * fmaf(y0, y0, fmaf(y1, y1, y2 * y2));
        ms[slot][r]  = ((y0 + y1 + y2) != 0.0f) ? 1.0f : 0.0f;
    }
    __syncthreads();

    const int jc = (t & 15) << 2;     // first of 4 adjacent j columns
    const int rg = t >> 4;            // 0..15

    float sd = 0.0f, so = 0.0f;       // diagonal-pair / off-diagonal-pair sums

#pragma unroll 1
    for (int pp = 0; pp < 2; ++pp) {
        const int isl = pp * 2, jsl = pp * 2 + 1;
        const bool diag = pp ? (ti1 == tj1) : (ti0 == tj0);
        float tp = 0.0f;

#pragma unroll
        for (int half = 0; half < 2; ++half) {
            const int i0 = half * 64 + rg * 4;
            const float4 v_xx = *(const float4*)&xsx[isl][i0];
            const float4 v_xy = *(const float4*)&xsy[isl][i0];
            const float4 v_xz = *(const float4*)&xsz[isl][i0];
            const float4 v_yx = *(const float4*)&ysx[isl][i0];
            const float4 v_yy = *(const float4*)&ysy[isl][i0];
            const float4 v_yz = *(const float4*)&ysz[isl][i0];
            const float4 v_hx = *(const float4*)&nhx[isl][i0];
            const float4 v_hy = *(const float4*)&nhy[isl][i0];
            const float4 v_mi = *(const float4*)&ms[isl][i0];
            const float xix[4] = { v_xx.x, v_xx.y, v_xx.z, v_xx.w };
            const float xiy[4] = { v_xy.x, v_xy.y, v_xy.z, v_xy.w };
            const float xiz[4] = { v_xz.x, v_xz.y, v_xz.z, v_xz.w };
            const float yix[4] = { v_yx.x, v_yx.y, v_yx.z, v_yx.w };
            const float yiy[4] = { v_yy.x, v_yy.y, v_yy.z, v_yy.w };
            const float yiz[4] = { v_yz.x, v_yz.y, v_yz.z, v_yz.w };
            const float hxi[4] = { v_hx.x, v_hx.y, v_hx.z, v_hx.w };
            const float hyi[4] = { v_hy.x, v_hy.y, v_hy.z, v_hy.w };
            const float mir[4] = { v_mi.x, v_mi.y, v_mi.z, v_mi.w };

            v2 acc[4];
#pragma unroll
            for (int r = 0; r < 4; ++r) acc[r] = splat2(0.0f);

#pragma unroll
            for (int jj = 0; jj < 2; ++jj) {
                const int j0 = jj * 64 + jc;
                const float4 xjx4 = *(const float4*)&xsx[jsl][j0];
                const float4 xjy4 = *(const float4*)&xsy[jsl][j0];
                const float4 xjz4 = *(const float4*)&xsz[jsl][j0];
                const float4 yjx4 = *(const float4*)&ysx[jsl][j0];
                const float4 yjy4 = *(const float4*)&ysy[jsl][j0];
                const float4 yjz4 = *(const float4*)&ysz[jsl][j0];
                const float4 hxj4 = *(const float4*)&nhx[jsl][j0];
                const float4 hyj4 = *(const float4*)&nhy[jsl][j0];
                const float4 mj4  = *(const float4*)&ms[jsl][j0];
#pragma unroll
                for (int s = 0; s < 2; ++s) {
                    const v2 xjx = s ? hi2(xjx4) : lo2(xjx4);
                    const v2 xjy = s ? hi2(xjy4) : lo2(xjy4);
                    const v2 xjz = s ? hi2(xjz4) : lo2(xjz4);
                    const v2 yjx = s ? hi2(yjx4) : lo2(yjx4);
                    const v2 yjy = s ? hi2(yjy4) : lo2(yjy4);
                    const v2 yjz = s ? hi2(yjz4) : lo2(yjz4);
                    const v2 hxj = s ? hi2(hxj4) : lo2(hxj4);
                    const v2 hyj = s ? hi2(hyj4) : lo2(hyj4);
                    const v2 mj  = s ? hi2(mj4)  : lo2(mj4);
#pragma unroll
                    for (int r = 0; r < 4; ++r) {
                        v2 ux = splat2(hxi[r]) + hxj;
                        ux = splat2(xix[r]) * xjx + ux;
                        ux = splat2(xiy[r]) * xjy + ux;
                        ux = splat2(xiz[r]) * xjz + ux;
                        v2 uy = splat2(hyi[r]) + hyj;
                        uy = splat2(yix[r]) * yjx + uy;
                        uy = splat2(yiy[r]) * yjy + uy;
                        uy = splat2(yiz[r]) * yjz + uy;
                        const v2 pr = ux * uy;           // >= 0 up to rounding
                        v2 sq;                           // |.| folds into VOP3 mod
                        sq.x = __builtin_amdgcn_sqrtf(__builtin_fabsf(pr.x));
                        sq.y = __builtin_amdgcn_sqrtf(__builtin_fabsf(pr.y));
                        acc[r] = mj * sq + acc[r];       // col mask
                    }
                }
            }
#pragma unroll
            for (int r = 0; r < 4; ++r)
                tp = fmaf(acc[r].x + acc[r].y, mir[r], tp);   // row mask
        }
        if (diag) sd += tp; else so += tp;
    }
    // x2 from sqrt(d2x*d2y)=2*sqrt(ux*uy); extra x2 off-diag for both orders
    float total = fmaf(so, 4.0f, sd * 2.0f);

    // ---- block reduction ----
#pragma unroll
    for (int off = 32; off > 0; off >>= 1)
        total += __shfl_down(total, off, 64);
    const int wave = t >> 6;
    if ((t & 63) == 0) red[wave] = total;
    __syncthreads();
    if (t == 0)
        partials[(size_t)g * Bp + b] = red[0] + red[1] + red[2] + red[3];
}

// Single wave: combine closed-form (d2x+d2y) term with cross-term partials.
__global__ __launch_bounds__(64) void drmsd_final(
    const float* __restrict__ partials, const float* __restrict__ moments,
    float* __restrict__ out)
{
    const int b = threadIdx.x;   // 0..63, one batch per lane
    double cross = 0.0;
#pragma unroll
    for (int gg = 0; gg < NCB; ++gg)
        cross += (double)partials[(size_t)gg * Bp + b];   // coalesced

    const float* mo = moments + (size_t)b * 9;
    const double sx0 = mo[0], sx1 = mo[1], sx2 = mo[2], qx = mo[3];
    const double sy0 = mo[4], sy1 = mo[5], sy2 = mo[6], qy = mo[7];
    const double M   = mo[8];
    const double term1 = 2.0 * M * (qx + qy)
        - 2.0 * (sx0*sx0 + sx1*sx1 + sx2*sx2 + sy0*sy0 + sy1*sy1 + sy2*sy2);

    double su = term1 - 2.0 * cross;
    su = su > 0.0 ? su : 0.0;        // guard rounding when x == y
    double pb = sqrt(su);
#pragma unroll
    for (int off = 32; off > 0; off >>= 1)
        pb += __shfl_down(pb, off, 64);
    if (b == 0) {
        const double denom = sqrt((double)Lp * (double)Lp / 2.0 - (double)Lp);
        out[0] = (float)(pb / denom / (double)Bp);
    }
}

extern "C" void kernel_launch(void* const* d_in, const int* in_sizes, int n_in,
                              void* d_out, int out_size, void* d_ws, size_t ws_size,
                              hipStream_t stream) {
    const float* x = (const float*)d_in[0];
    const float* y = (const float*)d_in[1];
    float* out      = (float*)d_out;
    float* partials = (float*)d_ws;                   // NCB*Bp floats
    float* moments  = partials + NCB * Bp;            // Bp*9 floats

    dim3 grid(Bp, NCB + 1);
    drmsd_main<<<grid, 256, 0, stream>>>(x, y, partials, moments);
    drmsd_final<<<1, 64, 0, stream>>>(partials, moments, out);
}

// Round 10
// 69.592 us; speedup vs baseline: 1.4978x; 1.0252x over previous
//
#include <hip/hip_runtime.h>
#include <math.h>

// Problem constants (match reference)
#define Lp 1024
#define Bp 64
#define Tt 128          // tile rows
#define NTILE 8         // Lp / Tt
#define NPAIR 36        // NTILE*(NTILE+1)/2 triangular tile pairs

typedef float v2 __attribute__((ext_vector_type(2)));
static __device__ __forceinline__ v2 splat2(float s) { v2 r; r.x = s; r.y = s; return r; }
static __device__ __forceinline__ v2 lo2(float4 v)   { v2 r; r.x = v.x; r.y = v.y; return r; }
static __device__ __forceinline__ v2 hi2(float4 v)   { v2 r; r.x = v.z; r.y = v.w; return r; }

// Identity: sum_{pairs} mi*mj*(dx-dy)^2
//         = sum mi*mj*(d2x+d2y)  -  2*sum mi*mj*dx*dy   (first term O(L) via moments)
// Cross term per pair: d2x = -2*ux, ux = xi.xj - |xi|^2/2 - |xj|^2/2  (ux <= 0 exact)
//   sqrt(d2x*d2y) = 2*sqrt(ux*uy); the 2 is folded into the block-partial scale.
// ux costs 4 fp32 ops (1 add + 3 fma) vs 6 for the subtract form; sqrt(|pr|)
// uses the free VOP3 abs modifier instead of a clamp. 10 VALU + 1 trans / pair.
//
// MEASURED-BEST configuration (68.7 us). Session ledger of failed variants:
//   j-hoist (+2.9), 2-batch/block (+63, spills), packed-stage+ticket final
//   (+35, same-address atomic serialization), whole-batch LDS (+4.5),
//   2-pairs/block (+2.6). Wall time is 59% harness workspace fill (40.2 us,
//   268 MB @ 84% achievable HBM); main's VALU-busy is ~7 us (R7 counters);
//   the rest is distributed latency/ramp with no surviving single lever.
//
// grid = (Bp, NPAIR+1): p < NPAIR  -> triangular tile-pair cross-term block
//                       p == NPAIR -> per-batch moment block (O(L) reductions)
__global__ __launch_bounds__(256) void drmsd_main(
    const float* __restrict__ x, const float* __restrict__ y,
    float* __restrict__ partials, float* __restrict__ moments)
{
    __shared__ __align__(16) float xsx[2][Tt], xsy[2][Tt], xsz[2][Tt];
    __shared__ __align__(16) float ysx[2][Tt], ysy[2][Tt], ysz[2][Tt];
    __shared__ __align__(16) float nhx[2][Tt], nhy[2][Tt];   // -|x|^2/2, -|y|^2/2
    __shared__ __align__(16) float ms[2][Tt];
    __shared__ float red[4];
    __shared__ float mred[4][9];

    const int b = blockIdx.x;      // batch
    const int p = blockIdx.y;      // pair index 0..35, or 36 = moment block
    const int t = threadIdx.x;

    if (p == NPAIR) {
        // ---- moment block: Sx(3), Qx, Sy(3), Qy, M for batch b ----
        float v[9];
#pragma unroll
        for (int k = 0; k < 9; ++k) v[k] = 0.0f;
#pragma unroll
        for (int k = 0; k < 4; ++k) {
            const int row = t + k * 256;
            const float* px = x + (size_t)row * (Bp * 3) + (size_t)b * 3;
            const float* py = y + (size_t)row * (Bp * 3) + (size_t)b * 3;
            const float x0 = px[0], x1 = px[1], x2 = px[2];
            const float y0 = py[0], y1 = py[1], y2 = py[2];
            const float m = ((y0 + y1 + y2) != 0.0f) ? 1.0f : 0.0f;
            v[0] += m * x0; v[1] += m * x1; v[2] += m * x2;
            v[3] = fmaf(m, fmaf(x0, x0, fmaf(x1, x1, x2 * x2)), v[3]);
            v[4] += m * y0; v[5] += m * y1; v[6] += m * y2;
            v[7] = fmaf(m, fmaf(y0, y0, fmaf(y1, y1, y2 * y2)), v[7]);
            v[8] += m;
        }
#pragma unroll
        for (int k = 0; k < 9; ++k) {
#pragma unroll
            for (int off = 32; off > 0; off >>= 1)
                v[k] += __shfl_down(v[k], off, 64);
        }
        const int wave = t >> 6;
        if ((t & 63) == 0) {
#pragma unroll
            for (int k = 0; k < 9; ++k) mred[wave][k] = v[k];
        }
        __syncthreads();
        if (t < 9)
            moments[(size_t)b * 9 + t] =
                mred[0][t] + mred[1][t] + mred[2][t] + mred[3][t];
        return;
    }

    // decode p -> (ti, tj), ti <= tj
    int ti = 0, base = 0;
    while (p >= base + (NTILE - ti)) { base += (NTILE - ti); ++ti; }
    const int tj = ti + (p - base);

    // ---- stage: threads 0-127 -> i-tile (slot 0), 128-255 -> j-tile (slot 1)
    {
        const int r     = t & (Tt - 1);
        const int which = t >> 7;
        const int tile  = which ? tj : ti;
        const int row   = tile * Tt + r;
        const float* px = x + (size_t)row * (Bp * 3) + (size_t)b * 3;
        const float* py = y + (size_t)row * (Bp * 3) + (size_t)b * 3;
        const float x0 = px[0], x1 = px[1], x2 = px[2];
        const float y0 = py[0], y1 = py[1], y2 = py[2];
        xsx[which][r] = x0; xsy[which][r] = x1; xsz[which][r] = x2;
        ysx[which][r] = y0; ysy[which][r] = y1; ysz[which][r] = y2;
        nhx[which][r] = -0.5f * fmaf(x0, x0, fmaf(x1, x1, x2 * x2));
        nhy[which][r] = -0.5f * fmaf(y0, y0, fmaf(y1, y1, y2 * y2));
        ms[which][r]  = ((y0 + y1 + y2) != 0.0f) ? 1.0f : 0.0f;
    }
    __syncthreads();

    const int jc = (t & 15) << 2;     // first of 4 adjacent j columns
    const int rg = t >> 4;            // 0..15

    float total = 0.0f;

#pragma unroll
    for (int half = 0; half < 2; ++half) {
        const int i0 = half * 64 + rg * 4;
        const float4 v_xx = *(const float4*)&xsx[0][i0];
        const float4 v_xy = *(const float4*)&xsy[0][i0];
        const float4 v_xz = *(const float4*)&xsz[0][i0];
        const float4 v_yx = *(const float4*)&ysx[0][i0];
        const float4 v_yy = *(const float4*)&ysy[0][i0];
        const float4 v_yz = *(const float4*)&ysz[0][i0];
        const float4 v_hx = *(const float4*)&nhx[0][i0];
        const float4 v_hy = *(const float4*)&nhy[0][i0];
        const float4 v_mi = *(const float4*)&ms[0][i0];
        const float xix[4] = { v_xx.x, v_xx.y, v_xx.z, v_xx.w };
        const float xiy[4] = { v_xy.x, v_xy.y, v_xy.z, v_xy.w };
        const float xiz[4] = { v_xz.x, v_xz.y, v_xz.z, v_xz.w };
        const float yix[4] = { v_yx.x, v_yx.y, v_yx.z, v_yx.w };
        const float yiy[4] = { v_yy.x, v_yy.y, v_yy.z, v_yy.w };
        const float yiz[4] = { v_yz.x, v_yz.y, v_yz.z, v_yz.w };
        const float hxi[4] = { v_hx.x, v_hx.y, v_hx.z, v_hx.w };
        const float hyi[4] = { v_hy.x, v_hy.y, v_hy.z, v_hy.w };
        const float mir[4] = { v_mi.x, v_mi.y, v_mi.z, v_mi.w };

        v2 acc[4];
#pragma unroll
        for (int r = 0; r < 4; ++r) acc[r] = splat2(0.0f);

#pragma unroll
        for (int jj = 0; jj < 2; ++jj) {
            const int j0 = jj * 64 + jc;
            const float4 xjx4 = *(const float4*)&xsx[1][j0];
            const float4 xjy4 = *(const float4*)&xsy[1][j0];
            const float4 xjz4 = *(const float4*)&xsz[1][j0];
            const float4 yjx4 = *(const float4*)&ysx[1][j0];
            const float4 yjy4 = *(const float4*)&ysy[1][j0];
            const float4 yjz4 = *(const float4*)&ysz[1][j0];
            const float4 hxj4 = *(const float4*)&nhx[1][j0];
            const float4 hyj4 = *(const float4*)&nhy[1][j0];
            const float4 mj4  = *(const float4*)&ms[1][j0];
#pragma unroll
            for (int s = 0; s < 2; ++s) {
                const v2 xjx = s ? hi2(xjx4) : lo2(xjx4);
                const v2 xjy = s ? hi2(xjy4) : lo2(xjy4);
                const v2 xjz = s ? hi2(xjz4) : lo2(xjz4);
                const v2 yjx = s ? hi2(yjx4) : lo2(yjx4);
                const v2 yjy = s ? hi2(yjy4) : lo2(yjy4);
                const v2 yjz = s ? hi2(yjz4) : lo2(yjz4);
                const v2 hxj = s ? hi2(hxj4) : lo2(hxj4);
                const v2 hyj = s ? hi2(hyj4) : lo2(hyj4);
                const v2 mj  = s ? hi2(mj4)  : lo2(mj4);
#pragma unroll
                for (int r = 0; r < 4; ++r) {
                    // ux = xi.xj - |xi|^2/2 - |xj|^2/2  (<= 0 in exact math)
                    v2 ux = splat2(hxi[r]) + hxj;                 // 1 add
                    ux = splat2(xix[r]) * xjx + ux;               // 3 fma
                    ux = splat2(xiy[r]) * xjy + ux;
                    ux = splat2(xiz[r]) * xjz + ux;
                    v2 uy = splat2(hyi[r]) + hyj;
                    uy = splat2(yix[r]) * yjx + uy;
                    uy = splat2(yiy[r]) * yjy + uy;
                    uy = splat2(yiz[r]) * yjz + uy;
                    const v2 pr = ux * uy;                        // >= 0 up to rounding
                    v2 sq;                                        // |.| folds into VOP3 mod
                    sq.x = __builtin_amdgcn_sqrtf(__builtin_fabsf(pr.x));
                    sq.y = __builtin_amdgcn_sqrtf(__builtin_fabsf(pr.y));
                    acc[r] = mj * sq + acc[r];                    // col mask, fma
                }
            }
        }
#pragma unroll
        for (int r = 0; r < 4; ++r)
            total = fmaf(acc[r].x + acc[r].y, mir[r], total);     // row mask
    }

    // ---- block reduction ----
#pragma unroll
    for (int off = 32; off > 0; off >>= 1)
        total += __shfl_down(total, off, 64);
    const int wave = t >> 6;
    if ((t & 63) == 0) red[wave] = total;
    __syncthreads();
    if (t == 0) {
        float s = red[0] + red[1] + red[2] + red[3];
        // x2: sqrt(d2x*d2y) = 2*sqrt(ux*uy); extra x2 off-diag for both orders
        s *= (ti != tj) ? 4.0f : 2.0f;
        partials[(size_t)p * Bp + b] = s;   // [p][b] layout -> coalesced final
    }
}

// Single wave: combine closed-form (d2x+d2y) term with cross-term partials.
__global__ __launch_bounds__(64) void drmsd_final(
    const float* __restrict__ partials, const float* __restrict__ moments,
    float* __restrict__ out)
{
    const int b = threadIdx.x;   // 0..63, one batch per lane
    double cross = 0.0;
#pragma unroll
    for (int pp = 0; pp < NPAIR; ++pp)
        cross += (double)partials[(size_t)pp * Bp + b];   // coalesced

    const float* mo = moments + (size_t)b * 9;
    const double sx0 = mo[0], sx1 = mo[1], sx2 = mo[2], qx = mo[3];
    const double sy0 = mo[4], sy1 = mo[5], sy2 = mo[6], qy = mo[7];
    const double M   = mo[8];
    const double term1 = 2.0 * M * (qx + qy)
        - 2.0 * (sx0*sx0 + sx1*sx1 + sx2*sx2 + sy0*sy0 + sy1*sy1 + sy2*sy2);

    double su = term1 - 2.0 * cross;
    su = su > 0.0 ? su : 0.0;        // guard rounding when x == y
    double pb = sqrt(su);
#pragma unroll
    for (int off = 32; off > 0; off >>= 1)
        pb += __shfl_down(pb, off, 64);
    if (b == 0) {
        const double denom = sqrt((double)Lp * (double)Lp / 2.0 - (double)Lp);
        out[0] = (float)(pb / denom / (double)Bp);
    }
}

extern "C" void kernel_launch(void* const* d_in, const int* in_sizes, int n_in,
                              void* d_out, int out_size, void* d_ws, size_t ws_size,
                              hipStream_t stream) {
    const float* x = (const float*)d_in[0];
    const float* y = (const float*)d_in[1];
    float* out      = (float*)d_out;
    float* partials = (float*)d_ws;                   // NPAIR*Bp floats
    float* moments  = partials + NPAIR * Bp;          // Bp*9 floats (total < 12 KB)

    dim3 grid(Bp, NPAIR + 1);
    drmsd_main<<<grid, 256, 0, stream>>>(x, y, partials, moments);
    drmsd_final<<<1, 64, 0, stream>>>(partials, moments, out);
}